// Round 2
// baseline (192.001 us; speedup 1.0000x reference)
//
#include <hip/hip_runtime.h>
#include <cfloat>

#define NN   1024
#define NE   16384
#define D0   128
#define EDIM 16
#define NH1  64
#define NOUT 40
#define KTOP 8
#define NEGINF (-1000000000.0f)

// ---- workspace layout (bytes); everything written before read, no memset needed ----
#define OFF_A    0u        // 1024 f
#define OFF_B    4096u     // 1024 f
#define OFF_DST  8192u     // 8192 int
#define OFF_EM   40960u    // 8192 int
#define OFF_H    73728u    // 1024*64 f

__device__ __forceinline__ void amx(float& v, int& j, float ov, int oj) {
    if (ov > v || (ov == v && oj < j)) { v = ov; j = oj; }
}

// a[i]=x[i]@w_node, b[i]=x[i]@w_nb — one wave per row, shfl reduce.
__global__ __launch_bounds__(256) void ab_kernel(
    const float* __restrict__ x, const float* __restrict__ mlp_w,
    float* __restrict__ a, float* __restrict__ b)
{
    int t = threadIdx.x, lane = t & 63, wid = t >> 6;
    int row = blockIdx.x * 4 + wid;
    const float* xr = x + row * D0;
    float x0 = xr[lane], x1 = xr[64 + lane];
    float sa = x0 * mlp_w[lane]       + x1 * mlp_w[64 + lane];
    float sb = x0 * mlp_w[128 + lane] + x1 * mlp_w[192 + lane];
    for (int s = 32; s; s >>= 1) { sa += __shfl_down(sa, s); sb += __shfl_down(sb, s); }
    if (lane == 0) { a[row] = sa; b[row] = sb; }
}

// Per row i: build LDS id grids by scanning edge list (last-wins max id for s_edge,
// first-wins min id for attr lookup), masked softmax, +gumbel, iterative top-8.
__global__ __launch_bounds__(256) void row_topk_kernel(
    const float* __restrict__ ea, const float* __restrict__ mlp_w,
    const float* __restrict__ mlp_b, const float* __restrict__ a,
    const float* __restrict__ b, const float* __restrict__ u,
    const int* __restrict__ ei, int* __restrict__ dsti, int* __restrict__ em)
{
    __shared__ float sv[NN];
    __shared__ int   idmx[NN];
    __shared__ int   idmn[NN];
    __shared__ float wred[4];
    __shared__ int   wredj[4];
    const int i = blockIdx.x, t = threadIdx.x;
    const int lane = t & 63, wid = t >> 6;

    for (int j = t; j < NN; j += 256) { idmx[j] = -1; idmn[j] = 0x7FFFFFFF; }
    __syncthreads();
    for (int e = t; e < NE; e += 256) {
        if (ei[e] == i) {
            int dj = ei[NE + e];
            atomicMax(&idmx[dj], e);
            atomicMin(&idmn[dj], e);
        }
    }
    __syncthreads();

    float we[EDIM];
    #pragma unroll
    for (int k = 0; k < EDIM; k++) we[k] = mlp_w[2 * D0 + k];
    const float bias = mlp_b[0];
    const float ai = a[i];

    // scores (same per-element math as the passing R1 version)
    float lmax = NEGINF;
    for (int j = t; j < NN; j += 256) {
        int id = idmx[j];
        float s;
        if (id >= 0) {
            float se = 0.f;
            #pragma unroll
            for (int k = 0; k < EDIM; k++) se += ea[id * EDIM + k] * we[k];
            s = ((ai + b[j]) + se) + bias;
        } else {
            s = NEGINF;
        }
        sv[j] = s;
        lmax = fmaxf(lmax, s);
    }
    for (int s = 32; s; s >>= 1) lmax = fmaxf(lmax, __shfl_down(lmax, s));
    if (lane == 0) wred[wid] = lmax;
    __syncthreads();
    float rowmax = fmaxf(fmaxf(wred[0], wred[1]), fmaxf(wred[2], wred[3]));
    bool noedge = (rowmax == NEGINF);
    __syncthreads();

    float lsum = 0.f;
    for (int j = t; j < NN; j += 256) {
        float evv;
        if (noedge) evv = 1.0f;
        else { float s = sv[j]; evv = (s == NEGINF) ? 0.0f : expf(s - rowmax); }
        sv[j] = evv;
        lsum += evv;
    }
    for (int s = 32; s; s >>= 1) lsum += __shfl_down(lsum, s);
    if (lane == 0) wred[wid] = lsum;
    __syncthreads();
    float rsum = wred[0] + wred[1] + wred[2] + wred[3];
    __syncthreads();

    for (int j = t; j < NN; j += 256) {
        float z = sv[j] / rsum;
        float uu = u[i * NN + j];
        float g = -logf(-logf(uu + 1e-20f) + 1e-20f);
        sv[j] = z + g;
    }
    __syncthreads();

    for (int sel = 0; sel < KTOP; sel++) {
        float bv = -FLT_MAX; int bj = NN;
        for (int j = t; j < NN; j += 256) amx(bv, bj, sv[j], j);
        for (int s = 32; s; s >>= 1) {
            float ov = __shfl_down(bv, s); int oj = __shfl_down(bj, s);
            amx(bv, bj, ov, oj);
        }
        if (lane == 0) { wred[wid] = bv; wredj[wid] = bj; }
        __syncthreads();
        if (t == 0) {
            float v = wred[0]; int j = wredj[0];
            amx(v, j, wred[1], wredj[1]);
            amx(v, j, wred[2], wredj[2]);
            amx(v, j, wred[3], wredj[3]);
            dsti[i * KTOP + sel] = j;
            int mn = idmn[j];
            em[i * KTOP + sel] = (mn == 0x7FFFFFFF) ? 0 : mn;
            sv[j] = -FLT_MAX;
        }
        __syncthreads();
    }
}

// GENConv1 fused: per dst node r — collect incoming edges (sorted for determinism),
// two deterministic passes (max, exp-sum) recomputing edge-proj, residual, MLP
// 128->256(relu)->64, outer relu -> h.
__global__ __launch_bounds__(128) void genconv1_kernel(
    const float* __restrict__ x, const float* __restrict__ ea,
    const float* __restrict__ we_g, const float* __restrict__ be,
    const float* __restrict__ w1, const float* __restrict__ b1,
    const float* __restrict__ w2, const float* __restrict__ b2,
    const int* __restrict__ dsti, const int* __restrict__ em,
    float* __restrict__ h)
{
    __shared__ int   slots[256];
    __shared__ float eatt[256 * EDIM];
    __shared__ float arow[D0];
    __shared__ float t1[2 * D0];
    __shared__ int   lcnt;
    const int r = blockIdx.x, t = threadIdx.x;
    if (t == 0) lcnt = 0;
    __syncthreads();
    for (int n = t; n < NN * KTOP; n += 128)
        if (dsti[n] == r) { int p = atomicAdd(&lcnt, 1); if (p < 256) slots[p] = n; }
    __syncthreads();
    int cnt = min(lcnt, 256);   // in-degree ~ Poisson(8); 256 cap is ~30-sigma safe
    if (t == 0) {
        for (int p = 1; p < cnt; p++) {
            int v = slots[p]; int q = p - 1;
            while (q >= 0 && slots[q] > v) { slots[q + 1] = slots[q]; q--; }
            slots[q + 1] = v;
        }
    }
    __syncthreads();
    for (int q = t; q < cnt * EDIM; q += 128)
        eatt[q] = ea[em[slots[q >> 4]] * EDIM + (q & 15)];
    __syncthreads();

    const int d = t;
    float wed[EDIM];
    #pragma unroll
    for (int k = 0; k < EDIM; k++) wed[k] = we_g[k * D0 + d];
    const float bed = be[d];

    float mxv = -FLT_MAX;
    for (int idx = 0; idx < cnt; idx++) {
        int n = slots[idx]; int src = n >> 3;
        float ep = bed;
        #pragma unroll
        for (int k = 0; k < EDIM; k++) ep += eatt[idx * EDIM + k] * wed[k];
        float m = fmaxf(x[src * D0 + d] + ep, 0.f) + 1e-7f;
        mxv = fmaxf(mxv, m);
    }
    float den = 0.f, num = 0.f;
    for (int idx = 0; idx < cnt; idx++) {
        int n = slots[idx]; int src = n >> 3;
        float ep = bed;
        #pragma unroll
        for (int k = 0; k < EDIM; k++) ep += eatt[idx * EDIM + k] * wed[k];
        float m = fmaxf(x[src * D0 + d] + ep, 0.f) + 1e-7f;
        float w = expf(m - mxv);
        den += w; num += w * m;
    }
    float agg = cnt ? num / (den > 0.f ? den : 1.f) : 0.f;
    arow[d] = agg + x[r * D0 + d];
    __syncthreads();

    float acc0 = b1[d], acc1 = b1[d + D0];
    for (int k = 0; k < D0; k++) {
        float av = arow[k];
        acc0 += av * w1[k * 2 * D0 + d];
        acc1 += av * w1[k * 2 * D0 + d + D0];
    }
    t1[d] = fmaxf(acc0, 0.f);
    t1[d + D0] = fmaxf(acc1, 0.f);
    __syncthreads();
    if (t < NH1) {
        float acc = b2[t];
        for (int k = 0; k < 2 * D0; k++) acc += t1[k] * w2[k * NH1 + t];
        h[r * NH1 + t] = fmaxf(acc, 0.f);   // GENConv out + outer relu
    }
}

// GENConv2 fused + head: agg over h, residual, MLP 64->128(relu)->64, outer relu,
// fc 64->40, node mask -> out.
__global__ __launch_bounds__(128) void genconv2_kernel(
    const float* __restrict__ h, const float* __restrict__ ea,
    const float* __restrict__ we_g, const float* __restrict__ be,
    const float* __restrict__ w1, const float* __restrict__ b1,
    const float* __restrict__ w2, const float* __restrict__ b2,
    const float* __restrict__ fcw, const float* __restrict__ fcb,
    const int* __restrict__ dsti, const int* __restrict__ em,
    const int* __restrict__ mask, float* __restrict__ out)
{
    __shared__ int   slots[256];
    __shared__ float eatt[256 * EDIM];
    __shared__ float arow[NH1];
    __shared__ float t2[2 * NH1];
    __shared__ float h2[NH1];
    __shared__ int   lcnt;
    const int r = blockIdx.x, t = threadIdx.x;
    if (t == 0) lcnt = 0;
    __syncthreads();
    for (int n = t; n < NN * KTOP; n += 128)
        if (dsti[n] == r) { int p = atomicAdd(&lcnt, 1); if (p < 256) slots[p] = n; }
    __syncthreads();
    int cnt = min(lcnt, 256);
    if (t == 0) {
        for (int p = 1; p < cnt; p++) {
            int v = slots[p]; int q = p - 1;
            while (q >= 0 && slots[q] > v) { slots[q + 1] = slots[q]; q--; }
            slots[q + 1] = v;
        }
    }
    __syncthreads();
    for (int q = t; q < cnt * EDIM; q += 128)
        eatt[q] = ea[em[slots[q >> 4]] * EDIM + (q & 15)];
    __syncthreads();

    if (t < NH1) {
        const int d = t;
        float wed[EDIM];
        #pragma unroll
        for (int k = 0; k < EDIM; k++) wed[k] = we_g[k * NH1 + d];
        const float bed = be[d];
        float mxv = -FLT_MAX;
        for (int idx = 0; idx < cnt; idx++) {
            int n = slots[idx]; int src = n >> 3;
            float ep = bed;
            #pragma unroll
            for (int k = 0; k < EDIM; k++) ep += eatt[idx * EDIM + k] * wed[k];
            float m = fmaxf(h[src * NH1 + d] + ep, 0.f) + 1e-7f;
            mxv = fmaxf(mxv, m);
        }
        float den = 0.f, num = 0.f;
        for (int idx = 0; idx < cnt; idx++) {
            int n = slots[idx]; int src = n >> 3;
            float ep = bed;
            #pragma unroll
            for (int k = 0; k < EDIM; k++) ep += eatt[idx * EDIM + k] * wed[k];
            float m = fmaxf(h[src * NH1 + d] + ep, 0.f) + 1e-7f;
            float w = expf(m - mxv);
            den += w; num += w * m;
        }
        float agg = cnt ? num / (den > 0.f ? den : 1.f) : 0.f;
        arow[d] = agg + h[r * NH1 + d];
    }
    __syncthreads();

    {   // MLP1: 64 -> 128, relu
        float acc = b1[t];
        for (int k = 0; k < NH1; k++) acc += arow[k] * w1[k * 2 * NH1 + t];
        t2[t] = fmaxf(acc, 0.f);
    }
    __syncthreads();
    if (t < NH1) {
        float acc = b2[t];
        for (int k = 0; k < 2 * NH1; k++) acc += t2[k] * w2[k * NH1 + t];
        h2[t] = fmaxf(acc, 0.f);   // outer relu
    }
    __syncthreads();
    if (t < NOUT) {
        float acc = fcb[t];
        for (int k = 0; k < NH1; k++) acc += h2[k] * fcw[k * NOUT + t];
        out[r * NOUT + t] = (mask[r] != 0) ? acc : 0.f;
    }
}

extern "C" void kernel_launch(void* const* d_in, const int* in_sizes, int n_in,
                              void* d_out, int out_size, void* d_ws, size_t ws_size,
                              hipStream_t stream) {
    const float* x      = (const float*)d_in[0];
    const float* ea     = (const float*)d_in[1];
    const float* u      = (const float*)d_in[2];
    const float* mlp_w  = (const float*)d_in[3];
    const float* mlp_b  = (const float*)d_in[4];
    const float* c1_we  = (const float*)d_in[5];
    const float* c1_be  = (const float*)d_in[6];
    const float* c1_w1  = (const float*)d_in[7];
    const float* c1_b1  = (const float*)d_in[8];
    const float* c1_w2  = (const float*)d_in[9];
    const float* c1_b2  = (const float*)d_in[10];
    const float* c2_we  = (const float*)d_in[11];
    const float* c2_be  = (const float*)d_in[12];
    const float* c2_w1  = (const float*)d_in[13];
    const float* c2_b1  = (const float*)d_in[14];
    const float* c2_w2  = (const float*)d_in[15];
    const float* c2_b2  = (const float*)d_in[16];
    const float* fc_w   = (const float*)d_in[17];
    const float* fc_b   = (const float*)d_in[18];
    const int*   ei     = (const int*)d_in[20];
    const int*   mask   = (const int*)d_in[21];

    char* ws = (char*)d_ws;
    float* a    = (float*)(ws + OFF_A);
    float* b    = (float*)(ws + OFF_B);
    int*   dsti = (int*)(ws + OFF_DST);
    int*   em   = (int*)(ws + OFF_EM);
    float* h    = (float*)(ws + OFF_H);
    float* out  = (float*)d_out;

    ab_kernel<<<NN / 4, 256, 0, stream>>>(x, mlp_w, a, b);
    row_topk_kernel<<<NN, 256, 0, stream>>>(ea, mlp_w, mlp_b, a, b, u, ei, dsti, em);
    genconv1_kernel<<<NN, 128, 0, stream>>>(x, ea, c1_we, c1_be, c1_w1, c1_b1, c1_w2, c1_b2,
                                            dsti, em, h);
    genconv2_kernel<<<NN, 128, 0, stream>>>(h, ea, c2_we, c2_be, c2_w1, c2_b1, c2_w2, c2_b2,
                                            fc_w, fc_b, dsti, em, mask, out);
}

// Round 3
// 165.295 us; speedup vs baseline: 1.1616x; 1.1616x over previous
//
#include <hip/hip_runtime.h>
#include <cfloat>

#define NN   1024
#define NE   16384
#define D0   128
#define EDIM 16
#define NH1  64
#define NOUT 40
#define KTOP 8
#define NEGINF (-1000000000.0f)
#define MAXDEG 64   // in-degree ~ Poisson(<=10); P(>64) astronomically small; clamped like R2

// ---- workspace layout (bytes) ----
#define OFF_IDMAX 0u          // 4 MB int   (last-edge-wins)
#define OFF_IDMIN 4194304u    // 4 MB uint  (first-edge-wins)
#define OFF_SE    8388608u    // NE f  (per-edge score dot)
#define OFF_A     8454144u    // 1024 f
#define OFF_B     8458240u    // 1024 f
#define OFF_DST   8462336u    // 8192 int
#define OFF_EM    8495104u    // 8192 int
#define OFF_RS    8527872u    // 1025 int (csr row starts)
#define OFF_SLOT  8536064u    // 8192 int (csr slots)
#define OFF_H     8568832u    // 1024*64 f

__device__ __forceinline__ void amx(float& v, int& j, float ov, int oj) {
    if (ov > v || (ov == v && oj < j)) { v = ov; j = oj; }
}

// blocks 0..63: per-edge scatter + se[e]=ea[e]@w_e ; blocks 64..319: a,b row dots.
__global__ __launch_bounds__(256) void prep_kernel(
    const float* __restrict__ x, const float* __restrict__ ea,
    const float* __restrict__ mlp_w, const int* __restrict__ ei,
    int* __restrict__ idmax, unsigned* __restrict__ idmin,
    float* __restrict__ se, float* __restrict__ a, float* __restrict__ b)
{
    int bid = blockIdx.x, t = threadIdx.x;
    if (bid < 64) {
        int e = bid * 256 + t;
        int s = ei[e], d = ei[NE + e];
        atomicMax(idmax + s * NN + d, e);
        atomicMin(idmin + s * NN + d, (unsigned)e);
        float acc = 0.f;
        #pragma unroll
        for (int k = 0; k < EDIM; k++) acc += ea[e * EDIM + k] * mlp_w[2 * D0 + k];
        se[e] = acc;
    } else {
        int lane = t & 63, wid = t >> 6;
        int row = (bid - 64) * 4 + wid;
        const float* xr = x + row * D0;
        float x0 = xr[lane], x1 = xr[64 + lane];
        float sa = x0 * mlp_w[lane]       + x1 * mlp_w[64 + lane];
        float sb = x0 * mlp_w[128 + lane] + x1 * mlp_w[192 + lane];
        for (int s2 = 32; s2; s2 >>= 1) { sa += __shfl_down(sa, s2); sb += __shfl_down(sb, s2); }
        if (lane == 0) { a[row] = sa; b[row] = sb; }
    }
}

// Per row i: scores from grid row + se, masked softmax, +gumbel, top-8.
__global__ __launch_bounds__(256) void row_topk_kernel(
    const int* __restrict__ idmax, const unsigned* __restrict__ idmin,
    const float* __restrict__ se, const float* __restrict__ mlp_b,
    const float* __restrict__ a, const float* __restrict__ b,
    const float* __restrict__ u, int* __restrict__ dsti, int* __restrict__ em)
{
    __shared__ float sv[NN];
    __shared__ unsigned idl[NN];
    __shared__ float wred[4];
    __shared__ int   wredj[4];
    const int i = blockIdx.x, t = threadIdx.x;
    const int lane = t & 63, wid = t >> 6;
    const int rowoff = i * NN;
    const float bias = mlp_b[0];
    const float ai = a[i];

    float lmax = NEGINF;
    #pragma unroll
    for (int q = 0; q < 4; q++) {
        int j = t + q * 256;
        int id = idmax[rowoff + j];
        float s = (id >= 0) ? (((ai + b[j]) + se[id]) + bias) : NEGINF;
        sv[j] = s;
        lmax = fmaxf(lmax, s);
    }
    for (int s = 32; s; s >>= 1) lmax = fmaxf(lmax, __shfl_down(lmax, s));
    if (lane == 0) wred[wid] = lmax;
    __syncthreads();
    float rowmax = fmaxf(fmaxf(wred[0], wred[1]), fmaxf(wred[2], wred[3]));
    bool noedge = (rowmax == NEGINF);
    __syncthreads();

    float lsum = 0.f;
    #pragma unroll
    for (int q = 0; q < 4; q++) {
        int j = t + q * 256;
        float evv;
        if (noedge) evv = 1.0f;
        else { float s = sv[j]; evv = (s == NEGINF) ? 0.0f : expf(s - rowmax); }
        sv[j] = evv;
        lsum += evv;
        idl[j] = idmin[rowoff + j];   // prefetch idmin row into LDS
    }
    for (int s = 32; s; s >>= 1) lsum += __shfl_down(lsum, s);
    if (lane == 0) wred[wid] = lsum;
    __syncthreads();
    float rsum = wred[0] + wred[1] + wred[2] + wred[3];
    __syncthreads();

    #pragma unroll
    for (int q = 0; q < 4; q++) {
        int j = t + q * 256;
        float z = sv[j] / rsum;
        float uu = u[rowoff + j];
        float g = -logf(-logf(uu + 1e-20f) + 1e-20f);
        sv[j] = z + g;
    }
    __syncthreads();

    for (int sel = 0; sel < KTOP; sel++) {
        float bv = -FLT_MAX; int bj = NN;
        #pragma unroll
        for (int q = 0; q < 4; q++) { int j = t + q * 256; amx(bv, bj, sv[j], j); }
        for (int s = 32; s; s >>= 1) {
            float ov = __shfl_down(bv, s); int oj = __shfl_down(bj, s);
            amx(bv, bj, ov, oj);
        }
        if (lane == 0) { wred[wid] = bv; wredj[wid] = bj; }
        __syncthreads();
        if (t == 0) {
            float v = wred[0]; int j = wredj[0];
            amx(v, j, wred[1], wredj[1]);
            amx(v, j, wred[2], wredj[2]);
            amx(v, j, wred[3], wredj[3]);
            dsti[i * KTOP + sel] = j;
            unsigned mn = idl[j];
            em[i * KTOP + sel] = (mn == 0xFFFFFFFFu) ? 0 : (int)mn;
            sv[j] = -FLT_MAX;
        }
        __syncthreads();
    }
}

// One block: CSR over dsti (count -> scan -> fill). slots order arbitrary; sorted by consumer.
__global__ __launch_bounds__(1024) void csr_kernel(
    const int* __restrict__ dsti, int* __restrict__ rs, int* __restrict__ slot)
{
    __shared__ int cnts[NN];
    __shared__ int sc[NN];
    __shared__ int ptr[NN];
    const int t = threadIdx.x;
    cnts[t] = 0;
    __syncthreads();
    int dloc[8];
    #pragma unroll
    for (int q = 0; q < 8; q++) {
        dloc[q] = dsti[q * NN + t];
        atomicAdd(&cnts[dloc[q]], 1);
    }
    __syncthreads();
    int v = cnts[t];
    sc[t] = v;
    __syncthreads();
    for (int off = 1; off < NN; off <<= 1) {
        int add = (t >= off) ? sc[t - off] : 0;
        __syncthreads();
        sc[t] += add;
        __syncthreads();
    }
    int excl = sc[t] - v;
    rs[t] = excl;
    if (t == NN - 1) rs[NN] = NE / 2;  // 8192
    ptr[t] = excl;
    __syncthreads();
    #pragma unroll
    for (int q = 0; q < 8; q++) {
        int n = q * NN + t;
        int p = atomicAdd(&ptr[dloc[q]], 1);
        slot[p] = n;
    }
}

// GENConv1 fused via CSR: 2 dst nodes per 256-thread block. d = t&127, sub = t>>7.
__global__ __launch_bounds__(256) void genconv1_kernel(
    const float* __restrict__ x, const float* __restrict__ ea,
    const float* __restrict__ we_g, const float* __restrict__ be,
    const float* __restrict__ w1, const float* __restrict__ b1,
    const float* __restrict__ w2, const float* __restrict__ b2,
    const int* __restrict__ rs, const int* __restrict__ slot,
    const int* __restrict__ em, float* __restrict__ h)
{
    __shared__ int   slots[2][MAXDEG];
    __shared__ float eatt[2][MAXDEG * EDIM];
    __shared__ float arow[2][D0];
    __shared__ float t1s[2][2 * D0];
    const int t = threadIdx.x, sub = t >> 7, d = t & 127;
    const int r = blockIdx.x * 2 + sub;
    const int beg = rs[r];
    const int cnt = min(rs[r + 1] - beg, MAXDEG);
    if (d < cnt) slots[sub][d] = slot[beg + d];
    __syncthreads();
    if (d == 0) {  // ascending-n order (deterministic, matches R2)
        for (int p = 1; p < cnt; p++) {
            int v = slots[sub][p]; int q = p - 1;
            while (q >= 0 && slots[sub][q] > v) { slots[sub][q + 1] = slots[sub][q]; q--; }
            slots[sub][q + 1] = v;
        }
    }
    __syncthreads();
    for (int q = d; q < cnt * EDIM; q += 128)
        eatt[sub][q] = ea[em[slots[sub][q >> 4]] * EDIM + (q & 15)];
    __syncthreads();

    float wed[EDIM];
    #pragma unroll
    for (int k = 0; k < EDIM; k++) wed[k] = we_g[k * D0 + d];
    const float bed = be[d];

    float mxv = -FLT_MAX;
    for (int idx = 0; idx < cnt; idx++) {
        int src = slots[sub][idx] >> 3;
        float ep = bed;
        #pragma unroll
        for (int k = 0; k < EDIM; k++) ep += eatt[sub][idx * EDIM + k] * wed[k];
        float m = fmaxf(x[src * D0 + d] + ep, 0.f) + 1e-7f;
        mxv = fmaxf(mxv, m);
    }
    float den = 0.f, num = 0.f;
    for (int idx = 0; idx < cnt; idx++) {
        int src = slots[sub][idx] >> 3;
        float ep = bed;
        #pragma unroll
        for (int k = 0; k < EDIM; k++) ep += eatt[sub][idx * EDIM + k] * wed[k];
        float m = fmaxf(x[src * D0 + d] + ep, 0.f) + 1e-7f;
        float w = expf(m - mxv);
        den += w; num += w * m;
    }
    float agg = cnt ? num / (den > 0.f ? den : 1.f) : 0.f;
    arow[sub][d] = agg + x[r * D0 + d];
    __syncthreads();

    float acc0 = b1[d], acc1 = b1[d + D0];
    for (int k = 0; k < D0; k++) {
        float av = arow[sub][k];
        acc0 += av * w1[k * 2 * D0 + d];
        acc1 += av * w1[k * 2 * D0 + d + D0];
    }
    t1s[sub][d] = fmaxf(acc0, 0.f);
    t1s[sub][d + D0] = fmaxf(acc1, 0.f);
    __syncthreads();
    if (d < NH1) {
        float acc = b2[d];
        for (int k = 0; k < 2 * D0; k++) acc += t1s[sub][k] * w2[k * NH1 + d];
        h[r * NH1 + d] = fmaxf(acc, 0.f);
    }
}

// GENConv2 fused + head via CSR: 4 dst nodes per 256-thread block. d = t&63, sub = t>>6.
__global__ __launch_bounds__(256) void genconv2_kernel(
    const float* __restrict__ h, const float* __restrict__ ea,
    const float* __restrict__ we_g, const float* __restrict__ be,
    const float* __restrict__ w1, const float* __restrict__ b1,
    const float* __restrict__ w2, const float* __restrict__ b2,
    const float* __restrict__ fcw, const float* __restrict__ fcb,
    const int* __restrict__ rs, const int* __restrict__ slot,
    const int* __restrict__ em, const int* __restrict__ mask,
    float* __restrict__ out)
{
    __shared__ int   slots[4][MAXDEG];
    __shared__ float eatt[4][MAXDEG * EDIM];
    __shared__ float arow[4][NH1];
    __shared__ float t2s[4][2 * NH1];
    __shared__ float h2s[4][NH1];
    const int t = threadIdx.x, sub = t >> 6, d = t & 63;
    const int r = blockIdx.x * 4 + sub;
    const int beg = rs[r];
    const int cnt = min(rs[r + 1] - beg, MAXDEG);
    if (d < cnt) slots[sub][d] = slot[beg + d];
    __syncthreads();
    if (d == 0) {
        for (int p = 1; p < cnt; p++) {
            int v = slots[sub][p]; int q = p - 1;
            while (q >= 0 && slots[sub][q] > v) { slots[sub][q + 1] = slots[sub][q]; q--; }
            slots[sub][q + 1] = v;
        }
    }
    __syncthreads();
    for (int q = d; q < cnt * EDIM; q += 64)
        eatt[sub][q] = ea[em[slots[sub][q >> 4]] * EDIM + (q & 15)];
    __syncthreads();

    float wed[EDIM];
    #pragma unroll
    for (int k = 0; k < EDIM; k++) wed[k] = we_g[k * NH1 + d];
    const float bed = be[d];

    float mxv = -FLT_MAX;
    for (int idx = 0; idx < cnt; idx++) {
        int src = slots[sub][idx] >> 3;
        float ep = bed;
        #pragma unroll
        for (int k = 0; k < EDIM; k++) ep += eatt[sub][idx * EDIM + k] * wed[k];
        float m = fmaxf(h[src * NH1 + d] + ep, 0.f) + 1e-7f;
        mxv = fmaxf(mxv, m);
    }
    float den = 0.f, num = 0.f;
    for (int idx = 0; idx < cnt; idx++) {
        int src = slots[sub][idx] >> 3;
        float ep = bed;
        #pragma unroll
        for (int k = 0; k < EDIM; k++) ep += eatt[sub][idx * EDIM + k] * wed[k];
        float m = fmaxf(h[src * NH1 + d] + ep, 0.f) + 1e-7f;
        float w = expf(m - mxv);
        den += w; num += w * m;
    }
    float agg = cnt ? num / (den > 0.f ? den : 1.f) : 0.f;
    arow[sub][d] = agg + h[r * NH1 + d];
    __syncthreads();

    {   // MLP1: 64 -> 128 (each thread computes outputs d and d+64; same k-order as before)
        float acc_a = b1[d], acc_b = b1[d + NH1];
        for (int k = 0; k < NH1; k++) {
            float av = arow[sub][k];
            acc_a += av * w1[k * 2 * NH1 + d];
            acc_b += av * w1[k * 2 * NH1 + d + NH1];
        }
        t2s[sub][d] = fmaxf(acc_a, 0.f);
        t2s[sub][d + NH1] = fmaxf(acc_b, 0.f);
    }
    __syncthreads();
    {
        float acc = b2[d];
        for (int k = 0; k < 2 * NH1; k++) acc += t2s[sub][k] * w2[k * NH1 + d];
        h2s[sub][d] = fmaxf(acc, 0.f);
    }
    __syncthreads();
    if (d < NOUT) {
        float acc = fcb[d];
        for (int k = 0; k < NH1; k++) acc += h2s[sub][k] * fcw[k * NOUT + d];
        out[r * NOUT + d] = (mask[r] != 0) ? acc : 0.f;
    }
}

extern "C" void kernel_launch(void* const* d_in, const int* in_sizes, int n_in,
                              void* d_out, int out_size, void* d_ws, size_t ws_size,
                              hipStream_t stream) {
    const float* x      = (const float*)d_in[0];
    const float* ea     = (const float*)d_in[1];
    const float* u      = (const float*)d_in[2];
    const float* mlp_w  = (const float*)d_in[3];
    const float* mlp_b  = (const float*)d_in[4];
    const float* c1_we  = (const float*)d_in[5];
    const float* c1_be  = (const float*)d_in[6];
    const float* c1_w1  = (const float*)d_in[7];
    const float* c1_b1  = (const float*)d_in[8];
    const float* c1_w2  = (const float*)d_in[9];
    const float* c1_b2  = (const float*)d_in[10];
    const float* c2_we  = (const float*)d_in[11];
    const float* c2_be  = (const float*)d_in[12];
    const float* c2_w1  = (const float*)d_in[13];
    const float* c2_b1  = (const float*)d_in[14];
    const float* c2_w2  = (const float*)d_in[15];
    const float* c2_b2  = (const float*)d_in[16];
    const float* fc_w   = (const float*)d_in[17];
    const float* fc_b   = (const float*)d_in[18];
    const int*   ei     = (const int*)d_in[20];
    const int*   mask   = (const int*)d_in[21];

    char* ws = (char*)d_ws;
    int*      idmax = (int*)(ws + OFF_IDMAX);
    unsigned* idmin = (unsigned*)(ws + OFF_IDMIN);
    float* se   = (float*)(ws + OFF_SE);
    float* a    = (float*)(ws + OFF_A);
    float* b    = (float*)(ws + OFF_B);
    int*   dsti = (int*)(ws + OFF_DST);
    int*   em   = (int*)(ws + OFF_EM);
    int*   rs   = (int*)(ws + OFF_RS);
    int*   slot = (int*)(ws + OFF_SLOT);
    float* h    = (float*)(ws + OFF_H);
    float* out  = (float*)d_out;

    hipMemsetAsync(ws + OFF_IDMAX, 0xFF, 8388608u, stream);  // idmax=-1, idmin=UINT_MAX
    prep_kernel<<<320, 256, 0, stream>>>(x, ea, mlp_w, ei, idmax, idmin, se, a, b);
    row_topk_kernel<<<NN, 256, 0, stream>>>(idmax, idmin, se, mlp_b, a, b, u, dsti, em);
    csr_kernel<<<1, 1024, 0, stream>>>(dsti, rs, slot);
    genconv1_kernel<<<NN / 2, 256, 0, stream>>>(x, ea, c1_we, c1_be, c1_w1, c1_b1, c1_w2, c1_b2,
                                                rs, slot, em, h);
    genconv2_kernel<<<NN / 4, 256, 0, stream>>>(h, ea, c2_we, c2_be, c2_w1, c2_b1, c2_w2, c2_b2,
                                                fc_w, fc_b, rs, slot, em, mask, out);
}